// Round 1
// baseline (2007.495 us; speedup 1.0000x reference)
//
#include <hip/hip_runtime.h>
#include <cstdint>

// BitNet MLP: x[8192,4096] -> bitlinear(W1[16384,4096]) -> gelu -> bitlinear(W2[4096,16384])
// All matmuls done in int8 MFMA with int32 accumulation (exact, matches fp32 reference
// since all values are integers < 2^24).

#define EPSQ 1e-5f
#define NW_INV (1.0 / 67108864.0)   // both W have 2^26 elements (exact power of two)

typedef int v4i __attribute__((ext_vector_type(4)));

__device__ __forceinline__ void gload_lds16(const void* g, void* l) {
  __builtin_amdgcn_global_load_lds((const __attribute__((address_space(1))) void*)g,
                                   (__attribute__((address_space(3))) void*)l, 16, 0, 0);
}

__device__ __forceinline__ float wave_max(float v) {
#pragma unroll
  for (int o = 32; o; o >>= 1) v = fmaxf(v, __shfl_xor(v, o));
  return v;
}
__device__ __forceinline__ float wave_sum(float v) {
#pragma unroll
  for (int o = 32; o; o >>= 1) v += __shfl_xor(v, o);
  return v;
}
__device__ __forceinline__ uint32_t pack4i8(int a, int b, int c, int d) {
  return (uint32_t)(a & 255) | ((uint32_t)(b & 255) << 8) |
         ((uint32_t)(c & 255) << 16) | ((uint32_t)(d & 255) << 24);
}

// ---- K1: sum of |w| into double accumulator (grid-stride, block->atomic) ----
__global__ __launch_bounds__(256) void k_absum(const float4* __restrict__ w, long n4,
                                               double* __restrict__ out) {
  float s = 0.f;
  long stride = (long)gridDim.x * blockDim.x;
  for (long i = (long)blockIdx.x * blockDim.x + threadIdx.x; i < n4; i += stride) {
    float4 v = w[i];
    s += fabsf(v.x) + fabsf(v.y) + fabsf(v.z) + fabsf(v.w);
  }
  s = wave_sum(s);
  __shared__ float red[4];
  int lane = threadIdx.x & 63, wid = threadIdx.x >> 6;
  if (lane == 0) red[wid] = s;
  __syncthreads();
  if (threadIdx.x == 0) {
    double t = (double)red[0] + (double)red[1] + (double)red[2] + (double)red[3];
    atomicAdd(out, t);
  }
}

// ---- K2: ternary quantize W -> int8 {-1,0,1} ----
__global__ __launch_bounds__(256) void k_quantw(const float4* __restrict__ w,
                                                uint4* __restrict__ wq,
                                                const double* __restrict__ sum) {
  float sw = fmaxf((float)(*sum * NW_INV), EPSQ);
  long gid = (long)blockIdx.x * blockDim.x + threadIdx.x;
  int q[16];
#pragma unroll
  for (int j = 0; j < 4; ++j) {
    float4 v = w[gid * 4 + j];
    float f[4] = {v.x, v.y, v.z, v.w};
#pragma unroll
    for (int i = 0; i < 4; ++i) {
      float r = rintf(f[i] / sw);            // round half-to-even, like jnp.round
      r = fminf(fmaxf(r, -1.f), 1.f);
      q[j * 4 + i] = (int)r;
    }
  }
  uint4 o;
  o.x = pack4i8(q[0], q[1], q[2], q[3]);
  o.y = pack4i8(q[4], q[5], q[6], q[7]);
  o.z = pack4i8(q[8], q[9], q[10], q[11]);
  o.w = pack4i8(q[12], q[13], q[14], q[15]);
  wq[gid] = o;
}

// ---- K3: per-token quantize x (row of 4096) -> int8, write sx1[row] ----
__global__ __launch_bounds__(256) void k_quantx(const float* __restrict__ x,
                                                uint4* __restrict__ xq,
                                                float* __restrict__ sx) {
  long row = blockIdx.x;
  int tid = threadIdx.x;
  const float4* xr = (const float4*)(x + row * 4096);
  float f[16];
  float m = 0.f;
#pragma unroll
  for (int j = 0; j < 4; ++j) {
    float4 v = xr[tid * 4 + j];
    f[j * 4 + 0] = v.x; f[j * 4 + 1] = v.y; f[j * 4 + 2] = v.z; f[j * 4 + 3] = v.w;
    m = fmaxf(m, fmaxf(fmaxf(fabsf(v.x), fabsf(v.y)), fmaxf(fabsf(v.z), fabsf(v.w))));
  }
  m = wave_max(m);
  __shared__ float red[4];
  __shared__ float bmax;
  int lane = tid & 63, wid = tid >> 6;
  if (lane == 0) red[wid] = m;
  __syncthreads();
  if (tid == 0) {
    float bm = fmaxf(fmaxf(red[0], red[1]), fmaxf(red[2], red[3]));
    bmax = bm;
    sx[row] = fmaxf(bm, EPSQ) / 127.f;
  }
  __syncthreads();
  float sxv = fmaxf(bmax, EPSQ) / 127.f;
  int q[16];
#pragma unroll
  for (int i = 0; i < 16; ++i) {
    float r = rintf(f[i] / sxv);
    r = fminf(fmaxf(r, -128.f), 127.f);
    q[i] = (int)r;
  }
  uint4 o;
  o.x = pack4i8(q[0], q[1], q[2], q[3]);
  o.y = pack4i8(q[4], q[5], q[6], q[7]);
  o.z = pack4i8(q[8], q[9], q[10], q[11]);
  o.w = pack4i8(q[12], q[13], q[14], q[15]);
  xq[row * 256 + tid] = o;
}

// ---- K5: dequant h (int32), exact gelu, row absmax, requantize int8 IN PLACE ----
__global__ __launch_bounds__(1024) void k_geluq(int* __restrict__ h,
                                                const float* __restrict__ sx1,
                                                float* __restrict__ sx2,
                                                const double* __restrict__ sums) {
  long row = blockIdx.x;
  int tid = threadIdx.x;
  float sw1 = fmaxf((float)(sums[0] * NW_INV), EPSQ);
  float s1 = sx1[row];
  const int4* hr = (const int4*)(h + row * 16384);
  float g[16];
  float m = 0.f;
#pragma unroll
  for (int j = 0; j < 4; ++j) {
    int4 v = hr[tid * 4 + j];
    int a[4] = {v.x, v.y, v.z, v.w};
#pragma unroll
    for (int i = 0; i < 4; ++i) {
      float hf = ((float)a[i] * s1) * sw1;                       // matches (e*sx)*sw
      float gg = (hf * (erff(hf / 1.4142135623730951f) + 1.f)) * 0.5f;  // exact gelu
      g[j * 4 + i] = gg;
      m = fmaxf(m, fabsf(gg));
    }
  }
  m = wave_max(m);
  __shared__ float red[16];
  __shared__ float bscale;
  int lane = tid & 63, wid = tid >> 6;
  if (lane == 0) red[wid] = m;
  __syncthreads();
  if (tid == 0) {
    float bm = red[0];
#pragma unroll
    for (int i = 1; i < 16; ++i) bm = fmaxf(bm, red[i]);
    float sv = fmaxf(bm, EPSQ) / 127.f;
    bscale = sv;
    sx2[row] = sv;
  }
  __syncthreads();
  float sv = bscale;
  int q[16];
#pragma unroll
  for (int i = 0; i < 16; ++i) {
    float r = rintf(g[i] / sv);
    r = fminf(fmaxf(r, -128.f), 127.f);
    q[i] = (int)r;
  }
  uint4 o;
  o.x = pack4i8(q[0], q[1], q[2], q[3]);
  o.y = pack4i8(q[4], q[5], q[6], q[7]);
  o.z = pack4i8(q[8], q[9], q[10], q[11]);
  o.w = pack4i8(q[12], q[13], q[14], q[15]);
  // in-place: int8 row occupies first 16KB of the 64KB int32 row. All reads done
  // (registers) before the __syncthreads above; block owns the row exclusively.
  ((uint4*)((char*)h + row * 65536))[tid] = o;
}

// ---- int8 GEMM: C[M,N] = A[M,Kb] * B[N,Kb]^T  (both K-major int8) ----
// 128x128 tile, BK=128 bytes, 4 waves (2x2), mfma_i32_16x16x64_i8.
// LDS staged via global_load_lds(16B) with pre-swizzled global source
// (chunk ^ (row&7)) so ds_read_b128 is ~2-way-conflict-free.
template <int MODE>
__global__ __launch_bounds__(256, 2) void k_gemm(
    const signed char* __restrict__ A, long lda,
    const signed char* __restrict__ B, long ldb, int kb,
    int* __restrict__ Cint, long ldc_i,
    float* __restrict__ Cf, long ldc_f,
    const float* __restrict__ sxv, const double* __restrict__ swsum) {
  __shared__ __align__(16) signed char smA[128 * 128];
  __shared__ __align__(16) signed char smB[128 * 128];
  int tid = threadIdx.x;
  int tileM = blockIdx.y, tileN = blockIdx.x;
  const signed char* Abase = A + (long)tileM * 128 * lda;
  const signed char* Bbase = B + (long)tileN * 128 * ldb;
  int lane = tid & 63;
  int wid = tid >> 6;
  int wm = wid >> 1, wn = wid & 1;
  int lrow = lane & 15, lk = lane >> 4;

  v4i acc[4][4];
#pragma unroll
  for (int m = 0; m < 4; ++m)
#pragma unroll
    for (int n = 0; n < 4; ++n) acc[m][n] = (v4i){0, 0, 0, 0};

  int nkt = kb >> 7;
  for (int kt = 0; kt < nkt; ++kt) {
    long koff = (long)kt << 7;
#pragma unroll
    for (int t = 0; t < 4; ++t) {
      int c = t * 256 + tid;
      int row = c >> 3, cc = c & 7;
      int scc = cc ^ (row & 7);
      gload_lds16(Abase + (long)row * lda + koff + scc * 16, smA + c * 16);
      gload_lds16(Bbase + (long)row * ldb + koff + scc * 16, smB + c * 16);
    }
    __syncthreads();
#pragma unroll
    for (int ks = 0; ks < 2; ++ks) {
      v4i af[4], bf[4];
#pragma unroll
      for (int m = 0; m < 4; ++m) {
        int r = wm * 64 + m * 16 + lrow;
        int ch = (ks * 4 + lk) ^ (r & 7);
        af[m] = *(const v4i*)(smA + r * 128 + ch * 16);
      }
#pragma unroll
      for (int n = 0; n < 4; ++n) {
        int r = wn * 64 + n * 16 + lrow;
        int ch = (ks * 4 + lk) ^ (r & 7);
        bf[n] = *(const v4i*)(smB + r * 128 + ch * 16);
      }
#pragma unroll
      for (int m = 0; m < 4; ++m)
#pragma unroll
        for (int n = 0; n < 4; ++n)
          acc[m][n] = __builtin_amdgcn_mfma_i32_16x16x64_i8(af[m], bf[n], acc[m][n], 0, 0, 0);
    }
    __syncthreads();
  }

  // epilogue: C/D layout col=lane&15, row=(lane>>4)*4+reg (m89-verified)
  int colb = tileN * 128 + wn * 64;
  int rowb = tileM * 128 + wm * 64 + (lane >> 4) * 4;
  if (MODE == 0) {
#pragma unroll
    for (int m = 0; m < 4; ++m)
#pragma unroll
      for (int n = 0; n < 4; ++n) {
        int col = colb + n * 16 + (lane & 15);
        int r0 = rowb + m * 16;
#pragma unroll
        for (int rg = 0; rg < 4; ++rg)
          Cint[(long)(r0 + rg) * ldc_i + col] = acc[m][n][rg];
      }
  } else {
    float sw = fmaxf((float)(*swsum * NW_INV), EPSQ);
#pragma unroll
    for (int m = 0; m < 4; ++m)
#pragma unroll
      for (int n = 0; n < 4; ++n) {
        int col = colb + n * 16 + (lane & 15);
        int r0 = rowb + m * 16;
#pragma unroll
        for (int rg = 0; rg < 4; ++rg) {
          int r = r0 + rg;
          Cf[(long)r * ldc_f + col] = ((float)acc[m][n][rg] * sxv[r]) * sw;
        }
      }
  }
}

extern "C" void kernel_launch(void* const* d_in, const int* in_sizes, int n_in,
                              void* d_out, int out_size, void* d_ws, size_t ws_size,
                              hipStream_t stream) {
  const float* x = (const float*)d_in[0];    // [8192, 4096]
  const float* W1 = (const float*)d_in[1];   // [16384, 4096]
  const float* W2 = (const float*)d_in[2];   // [4096, 16384]
  float* out = (float*)d_out;                // [8192, 4096]

  char* ws = (char*)d_ws;
  double* sums = (double*)ws;                           // [2]
  signed char* wq1 = (signed char*)(ws + 256);          // 64 MB
  signed char* wq2 = wq1 + 67108864L;                   // 64 MB
  signed char* xq1 = wq2 + 67108864L;                   // 32 MB
  float* sx1 = (float*)(xq1 + 33554432L);               // 32 KB
  float* sx2 = sx1 + 8192;                              // 32 KB
  int* h = (int*)(ws + 167837952L);                     // 512 MB, [8192][16384] i32

  hipMemsetAsync(d_ws, 0, 64, stream);
  k_absum<<<4096, 256, 0, stream>>>((const float4*)W1, 16777216L, sums + 0);
  k_absum<<<4096, 256, 0, stream>>>((const float4*)W2, 16777216L, sums + 1);
  k_quantw<<<16384, 256, 0, stream>>>((const float4*)W1, (uint4*)wq1, sums + 0);
  k_quantw<<<16384, 256, 0, stream>>>((const float4*)W2, (uint4*)wq2, sums + 1);
  k_quantx<<<8192, 256, 0, stream>>>(x, (uint4*)xq1, sx1);

  dim3 g1(128, 64);  // N tiles x M tiles
  k_gemm<0><<<g1, 256, 0, stream>>>(xq1, 4096, wq1, 4096, 4096,
                                    h, 16384, nullptr, 0, nullptr, nullptr);

  k_geluq<<<8192, 1024, 0, stream>>>(h, sx1, sx2, sums);

  dim3 g2(32, 64);
  k_gemm<1><<<g2, 256, 0, stream>>>((const signed char*)h, 65536, wq2, 16384, 16384,
                                    nullptr, 0, out, 4096, sx2, sums + 1);
}